// Round 5
// baseline (67.240 us; speedup 1.0000x reference)
//
#include <hip/hip_runtime.h>

#define Bn 8
#define Nn 2048
#define Dn 128
#define OUTn 128

typedef __attribute__((ext_vector_type(8))) short bf16x8;     // MFMA A/B operand (8 bf16)
typedef __attribute__((ext_vector_type(8))) unsigned short ushort8;
typedef __attribute__((ext_vector_type(4))) float f32x4;      // MFMA C/D
typedef __attribute__((ext_vector_type(4))) float float4v;

__device__ __forceinline__ unsigned short f2bf(float f) {
  unsigned int u = __builtin_bit_cast(unsigned int, f);
  u += 0x7FFFu + ((u >> 16) & 1u);   // round-to-nearest-even
  return (unsigned short)(u >> 16);
}

// ================= K1: pack adj -> bits + degree; transpose input; transpose W ========
// blocks [0,4096): pack (1 wave = 1 adjacency row, lane-contiguous streaming)
// blocks [4096,4352): input [b][n][d] fp32 -> inT [b][d][n] bf16
// blocks [4352,4480): W [2D][OUT] fp32 -> WT [OUT][2D] bf16
__global__ __launch_bounds__(256) void gcn_prep(
    const float* __restrict__ in, const int* __restrict__ adj,
    const float* __restrict__ W, unsigned long long* __restrict__ adjP,
    float* __restrict__ deg, unsigned short* __restrict__ inT,
    unsigned short* __restrict__ WT) {
  __shared__ __attribute__((aligned(16))) unsigned short lds[64][130];
  const int tid = threadIdx.x;
  const int bid = blockIdx.x;

  if (bid < 4096) {
    // ---- pack: wave w handles global row bid*4+w ----
    const int wv = tid >> 6, l = tid & 63;
    const int row = bid * 4 + wv;                 // 0..16383 == b*N + n
    const int* rp = adj + (size_t)row * Nn;
    int v[32];
    #pragma unroll
    for (int k = 0; k < 32; ++k) v[k] = rp[k * 64 + l];   // lane-contiguous 256B/instr
    unsigned long long myw = 0;
    int cnt = 0;
    #pragma unroll
    for (int k = 0; k < 32; ++k) {
      unsigned long long w = __ballot(v[k] != 0);  // bit l == col k*64+l
      cnt += __popcll(w);                          // wave-uniform
      if (l == k) myw = w;
    }
    if (l < 32) adjP[(size_t)row * 32 + l] = myw;
    if (l == 0) deg[row] = (cnt == 0) ? 1.0f : (float)cnt;
    return;
  }
  if (bid < 4352) {
    // ---- transpose input ----
    const int b = (bid - 4096) >> 5;
    const int n0 = ((bid - 4096) & 31) * 64;
    #pragma unroll
    for (int c = 0; c < 32; ++c) {
      int e = tid + c * 256;
      int i = e >> 7, d = e & 127;
      lds[i][d] = f2bf(in[((size_t)(b * Nn + n0 + i)) * Dn + d]);
    }
    __syncthreads();
    #pragma unroll
    for (int c = 0; c < 4; ++c) {
      int ch = tid + c * 256;
      int d = ch >> 3, g = (ch & 7) * 8;
      ushort8 vv;
      #pragma unroll
      for (int e = 0; e < 8; ++e) vv[e] = lds[g + e][d];
      *(ushort8*)(inT + ((size_t)(b * Dn + d)) * Nn + n0 + g) = vv;
    }
    return;
  }
  // ---- WT ----
  int gid = (bid - 4352) * 256 + tid;              // 0..32767
  int j = gid >> 8, k = gid & 255;                 // WT[j][k] = W[k][j]
  WT[gid] = f2bf(W[k * OUTn + j]);
}

// ================= K2: GEMM from packed bits =================
// 256 blocks x 512 threads (8 waves). Block = 64 rows of one batch (XCD-swizzled:
// all 32 blocks of a batch land on one XCD -> adjP/inT panels L2-resident).
// wave wv: row-group rg=wv>>1 (16 rows), col-half chh=wv&1 (64 of 128 d-cols).
// A bits staged once in LDS (no K-loop barriers); B dbuf LDS, 1 barrier/iter,
// 2-deep register prefetch.
union SMem {
  struct {
    unsigned long long A[64][33];       // 16896 B, pitch 264B (conflict-free b64)
    unsigned short Bs[2][128][72];      // 36864 B, pitch 144B (2-way = free)
  } g;
  struct {
    unsigned short aggl[64][136];       // 17408 B
    float rowsum[64][2];
  } e;
};

__global__ __launch_bounds__(512, 2) void gcn_main(
    const float* __restrict__ input_, const unsigned long long* __restrict__ adjP,
    const float* __restrict__ deg, const float* __restrict__ bvec,
    const unsigned short* __restrict__ inT, const unsigned short* __restrict__ WT,
    float* __restrict__ out) {
  __shared__ SMem sm;
  const int tid = threadIdx.x;
  const int wv = tid >> 6;
  const int l = tid & 63, lr = l & 15, lg = l >> 4;
  const int rg = wv >> 1, chh = wv & 1;

  // bijective XCD swizzle: 256 blocks, XCD x -> batch x
  const int swz = (blockIdx.x & 7) * 32 + (blockIdx.x >> 3);
  const int bb = swz >> 5;
  const int row0 = (swz & 31) * 64;
  const int grow0 = bb * Nn + row0;

  // ---- stage A bits: 64 rows x 32 u64 words ----
  {
    const int r = tid >> 3, w8 = (tid & 7) * 4;
    const unsigned long long* src = adjP + (size_t)(grow0 + r) * 32 + w8;
    #pragma unroll
    for (int j = 0; j < 4; ++j) sm.g.A[r][w8 + j] = src[j];
  }

  const unsigned short* inTb = inT + (size_t)bb * Dn * Nn;
  const int bd = tid >> 3;             // d row (chunk c adds 64)
  const int koff = (tid & 7) * 8;

  // 2-deep B prefetch: breg[parity][chunk]
  ushort8 breg[2][2];
  #pragma unroll
  for (int c = 0; c < 2; ++c)
    breg[0][c] = *(const ushort8*)(inTb + (size_t)(bd + c * 64) * Nn + koff);
  #pragma unroll
  for (int c = 0; c < 2; ++c)
    breg[1][c] = *(const ushort8*)(inTb + (size_t)(bd + c * 64) * Nn + 64 + koff);

  f32x4 acc[4] = {};
  const int arow = rg * 16 + lr;

  #pragma unroll 2
  for (int it = 0; it < 32; ++it) {
    const int par = it & 1;
    // write tile it to Bs[par]
    #pragma unroll
    for (int c = 0; c < 2; ++c)
      *(ushort8*)&sm.g.Bs[par][bd + c * 64][koff] = breg[par][c];
    // issue tile it+2 loads into just-freed regs (2 iterations of latency cover)
    if (it + 2 < 32) {
      #pragma unroll
      for (int c = 0; c < 2; ++c)
        breg[par][c] = *(const ushort8*)(inTb + (size_t)(bd + c * 64) * Nn +
                                         (it + 2) * 64 + koff);
    }
    __syncthreads();                       // single barrier per iteration
    // A word for this K-tile; expand bits -> bf16 frags
    unsigned long long aw = sm.g.A[arow][it];
    #pragma unroll
    for (int kk = 0; kk < 2; ++kk) {
      unsigned int bits = (unsigned int)(aw >> (kk * 32 + lg * 8)) & 0xFFu;
      ushort8 av;
      #pragma unroll
      for (int e = 0; e < 8; ++e)
        av[e] = (bits & (1u << e)) ? (unsigned short)0x3F80u : (unsigned short)0u;
      bf16x8 af = __builtin_bit_cast(bf16x8, av);
      #pragma unroll
      for (int cf = 0; cf < 4; ++cf) {
        bf16x8 bfm = *(const bf16x8*)&sm.g.Bs[par][chh * 64 + cf * 16 + lr]
                                               [kk * 32 + lg * 8];
        acc[cf] = __builtin_amdgcn_mfma_f32_16x16x32_bf16(af, bfm, acc[cf], 0, 0, 0);
      }
    }
  }

  __syncthreads();                         // all GEMM1 LDS reads done; re-use as epi

  // ---- agg = acc/deg staged as bf16 ----
  float dg[4];
  #pragma unroll
  for (int reg = 0; reg < 4; ++reg)
    dg[reg] = deg[grow0 + rg * 16 + lg * 4 + reg];
  #pragma unroll
  for (int cf = 0; cf < 4; ++cf)
    #pragma unroll
    for (int reg = 0; reg < 4; ++reg)
      sm.e.aggl[rg * 16 + lg * 4 + reg][chh * 64 + cf * 16 + lr] =
          f2bf(acc[cf][reg] / dg[reg]);
  __syncthreads();

  // ---- GEMM2: [x | agg] @ W (K=256); x direct from input_, B from WT (L2-hot) ----
  f32x4 acc2[4] = {};
  const float* xrow = input_ + (size_t)(grow0 + rg * 16 + lr) * Dn;
  #pragma unroll
  for (int ks = 0; ks < 8; ++ks) {
    bf16x8 af;
    if (ks < 4) {
      float4v f0 = *(const float4v*)(xrow + ks * 32 + lg * 8);
      float4v f1 = *(const float4v*)(xrow + ks * 32 + lg * 8 + 4);
      ushort8 vv;
      #pragma unroll
      for (int e = 0; e < 4; ++e) { vv[e] = f2bf(f0[e]); vv[e + 4] = f2bf(f1[e]); }
      af = __builtin_bit_cast(bf16x8, vv);
    } else {
      af = *(const bf16x8*)&sm.e.aggl[rg * 16 + lr][(ks - 4) * 32 + lg * 8];
    }
    #pragma unroll
    for (int cf = 0; cf < 4; ++cf) {
      bf16x8 bw = *(const bf16x8*)(WT + (size_t)(chh * 64 + cf * 16 + lr) * 256 +
                                   ks * 32 + lg * 8);
      acc2[cf] = __builtin_amdgcn_mfma_f32_16x16x32_bf16(af, bw, acc2[cf], 0, 0, 0);
    }
  }

  // ---- bias + sigmoid + row L2-norm + store ----
  float bcol[4];
  #pragma unroll
  for (int cf = 0; cf < 4; ++cf) bcol[cf] = bvec[chh * 64 + cf * 16 + lr];
  float sg[4][4];
  #pragma unroll
  for (int cf = 0; cf < 4; ++cf)
    #pragma unroll
    for (int reg = 0; reg < 4; ++reg) {
      float x = acc2[cf][reg] + bcol[cf];
      sg[cf][reg] = 1.0f / (1.0f + expf(-x));
    }
  #pragma unroll
  for (int reg = 0; reg < 4; ++reg) {
    float p = 0.f;
    #pragma unroll
    for (int cf = 0; cf < 4; ++cf) p += sg[cf][reg] * sg[cf][reg];
    p += __shfl_xor(p, 1);
    p += __shfl_xor(p, 2);
    p += __shfl_xor(p, 4);
    p += __shfl_xor(p, 8);
    if (lr == 0) sm.e.rowsum[rg * 16 + lg * 4 + reg][chh] = p;
  }
  __syncthreads();
  #pragma unroll
  for (int reg = 0; reg < 4; ++reg) {
    const int row = rg * 16 + lg * 4 + reg;
    float inv = rsqrtf(sm.e.rowsum[row][0] + sm.e.rowsum[row][1]);
    #pragma unroll
    for (int cf = 0; cf < 4; ++cf)
      out[(size_t)(grow0 + row) * OUTn + chh * 64 + cf * 16 + lr] =
          sg[cf][reg] * inv;
  }
}

extern "C" void kernel_launch(void* const* d_in, const int* in_sizes, int n_in,
                              void* d_out, int out_size, void* d_ws, size_t ws_size,
                              hipStream_t stream) {
  (void)in_sizes; (void)n_in; (void)out_size; (void)ws_size;
  const float* input_ = (const float*)d_in[0];
  const int* adj = (const int*)d_in[1];
  const float* W = (const float*)d_in[2];
  const float* bvec = (const float*)d_in[3];
  float* out = (float*)d_out;

  // workspace layout (8.2 MB total):
  unsigned short* inT = (unsigned short*)d_ws;                          // 4 MB
  unsigned short* WT = inT + (size_t)Bn * Dn * Nn;                      // 64 KB
  unsigned long long* adjP =
      (unsigned long long*)((char*)d_ws + 4194304 + 65536);             // 4 MB
  float* deg = (float*)((char*)d_ws + 4194304 + 65536 + 4194304);       // 64 KB

  hipLaunchKernelGGL(gcn_prep, dim3(4480), dim3(256), 0, stream,
                     input_, adj, W, adjP, deg, inT, WT);
  hipLaunchKernelGGL(gcn_main, dim3(256), dim3(512), 0, stream,
                     input_, adjP, deg, bvec, inT, WT, out);
}